// Round 1
// baseline (771.483 us; speedup 1.0000x reference)
//
#include <hip/hip_runtime.h>

#define NFEAT 128
#define HID 16
#define NCLS 40

// K1: h1a = x @ W1  (N x 128 @ 128 x 16), also duplicate into agg1 (self-loop init)
__global__ __launch_bounds__(256) void gemm1_kernel(const float* __restrict__ x,
                                                    const float* __restrict__ W1,
                                                    float* __restrict__ h1a,
                                                    float* __restrict__ agg1, int n)
{
    // padded stride 132 floats: keeps 16B alignment, breaks power-of-2 bank aliasing
    __shared__ float xs[64 * 132];
    __shared__ float ws[16 * 132];
    int tid = threadIdx.x;
    int r0 = blockIdx.x * 64;
    int rows = n - r0; if (rows > 64) rows = 64;

    // load x tile (64 rows x 128 floats) coalesced as float4
    const float4* xg = (const float4*)(x + (size_t)r0 * NFEAT);
    #pragma unroll
    for (int i = 0; i < 8; ++i) {
        int flat4 = i * 256 + tid;          // float4 index, row-major 64x32
        int row = flat4 >> 5, k4 = flat4 & 31;
        float4 v = make_float4(0.f, 0.f, 0.f, 0.f);
        if (row < rows) v = xg[flat4];
        *(float4*)&xs[row * 132 + k4 * 4] = v;
    }
    // load W1 transposed: ws[c][k] = W1[k*16+c]
    for (int i = tid; i < HID * NFEAT; i += 256) {
        int c = i >> 7, k = i & 127;
        ws[c * 132 + k] = W1[k * HID + c];
    }
    __syncthreads();

    int row = tid >> 2;              // 0..63
    int c0  = (tid & 3) * 4;         // 0,4,8,12
    float acc[4] = {0.f, 0.f, 0.f, 0.f};
    #pragma unroll 4
    for (int k4 = 0; k4 < 32; ++k4) {
        float4 xv = *(const float4*)&xs[row * 132 + k4 * 4];
        #pragma unroll
        for (int i = 0; i < 4; ++i) {
            float4 wv = *(const float4*)&ws[(c0 + i) * 132 + k4 * 4];
            acc[i] += xv.x * wv.x + xv.y * wv.y + xv.z * wv.z + xv.w * wv.w;
        }
    }
    if (row < rows) {
        float4 o = make_float4(acc[0], acc[1], acc[2], acc[3]);
        size_t off = (size_t)(r0 + row) * HID + c0;
        *(float4*)&h1a[off]  = o;
        *(float4*)&agg1[off] = o;
    }
}

// K2/K4: agg[dst] += ew * h[src]  over 16-dim rows; 4 threads per edge, 4 atomics each
__global__ __launch_bounds__(256) void scatter16_kernel(const float* __restrict__ h,
                                                        float* __restrict__ agg,
                                                        const int* __restrict__ src,
                                                        const int* __restrict__ dst,
                                                        const float* __restrict__ ew, int nE)
{
    int gid = blockIdx.x * 256 + threadIdx.x;
    if (gid >= nE * 4) return;
    int e = gid >> 2, p = gid & 3;
    int s = src[e], d = dst[e];
    float w = ew[e];
    float4 v = ((const float4*)h)[s * 4 + p];
    float* a = agg + (size_t)d * HID + p * 4;
    atomicAdd(a + 0, v.x * w);
    atomicAdd(a + 1, v.y * w);
    atomicAdd(a + 2, v.z * w);
    atomicAdd(a + 3, v.w * w);
}

// K3: plain float4 copy (self-loop init for layer 2)
__global__ __launch_bounds__(256) void copy_kernel(const float4* __restrict__ in,
                                                   float4* __restrict__ out, int n4)
{
    int i = blockIdx.x * 256 + threadIdx.x;
    if (i < n4) out[i] = in[i];
}

// K5: out = log_softmax(agg2 @ W2)  per row; thread-per-row, W2 broadcast from LDS
__global__ __launch_bounds__(256) void gemm2_lsm_kernel(const float* __restrict__ h,
                                                        const float* __restrict__ W2,
                                                        float* __restrict__ out, int n)
{
    __shared__ float ws[HID * NCLS];   // 640 floats
    int tid = threadIdx.x;
    for (int i = tid; i < HID * NCLS; i += 256) ws[i] = W2[i];
    __syncthreads();
    int r = blockIdx.x * 256 + tid;
    if (r >= n) return;

    float hr[HID];
    const float4* h4 = (const float4*)(h + (size_t)r * HID);
    #pragma unroll
    for (int i = 0; i < 4; ++i) {
        float4 v = h4[i];
        hr[i * 4 + 0] = v.x; hr[i * 4 + 1] = v.y; hr[i * 4 + 2] = v.z; hr[i * 4 + 3] = v.w;
    }
    float acc[NCLS];
    #pragma unroll
    for (int j = 0; j < NCLS; ++j) acc[j] = 0.f;
    #pragma unroll
    for (int k = 0; k < HID; ++k) {
        float hk = hr[k];
        #pragma unroll
        for (int j4 = 0; j4 < NCLS / 4; ++j4) {
            float4 w = *(const float4*)&ws[k * NCLS + j4 * 4];
            acc[j4 * 4 + 0] += hk * w.x;
            acc[j4 * 4 + 1] += hk * w.y;
            acc[j4 * 4 + 2] += hk * w.z;
            acc[j4 * 4 + 3] += hk * w.w;
        }
    }
    float m = acc[0];
    #pragma unroll
    for (int j = 1; j < NCLS; ++j) m = fmaxf(m, acc[j]);
    float ssum = 0.f;
    #pragma unroll
    for (int j = 0; j < NCLS; ++j) ssum += __expf(acc[j] - m);
    float l = m + __logf(ssum);
    float4* o4 = (float4*)(out + (size_t)r * NCLS);
    #pragma unroll
    for (int j4 = 0; j4 < NCLS / 4; ++j4)
        o4[j4] = make_float4(acc[j4 * 4 + 0] - l, acc[j4 * 4 + 1] - l,
                             acc[j4 * 4 + 2] - l, acc[j4 * 4 + 3] - l);
}

extern "C" void kernel_launch(void* const* d_in, const int* in_sizes, int n_in,
                              void* d_out, int out_size, void* d_ws, size_t ws_size,
                              hipStream_t stream)
{
    const float* x  = (const float*)d_in[0];
    const float* ew = (const float*)d_in[1];
    const float* W1 = (const float*)d_in[2];
    const float* W2 = (const float*)d_in[3];
    const int*   ei = (const int*)d_in[4];

    int n = in_sizes[0] / NFEAT;     // 100000
    int E = in_sizes[1];             // 1600000
    const int* src = ei;
    const int* dst = ei + E;
    float* out = (float*)d_out;

    // workspace layout: [h1a | agg1], agg2 reuses h1a's slot after scatter1
    float* h1a  = (float*)d_ws;
    float* agg1 = h1a + (size_t)n * HID;
    float* agg2 = h1a;               // h1a dead after scatter1

    gemm1_kernel<<<(n + 63) / 64, 256, 0, stream>>>(x, W1, h1a, agg1, n);
    scatter16_kernel<<<(E * 4 + 255) / 256, 256, 0, stream>>>(h1a, agg1, src, dst, ew, E);
    copy_kernel<<<(n * 4 + 255) / 256, 256, 0, stream>>>((const float4*)agg1, (float4*)agg2, n * 4);
    scatter16_kernel<<<(E * 4 + 255) / 256, 256, 0, stream>>>(agg1, agg2, src, dst, ew, E);
    gemm2_lsm_kernel<<<(n + 255) / 256, 256, 0, stream>>>(agg2, W2, out, n);
}

// Round 2
// 387.464 us; speedup vs baseline: 1.9911x; 1.9911x over previous
//
#include <hip/hip_runtime.h>

#define NFEAT 128
#define HID 16
#define NCLS 40
#define SCAN_CHUNK 1024   // 256 threads x 4 elems

// ---------- CSR build ----------

__global__ __launch_bounds__(256) void zero_counts_kernel(int* __restrict__ cnt, int n)
{
    int i = blockIdx.x * 256 + threadIdx.x;
    if (i < n) cnt[i] = 0;
}

__global__ __launch_bounds__(256) void count_deg_kernel(const int* __restrict__ dst,
                                                        int* __restrict__ cnt, int E)
{
    int e = blockIdx.x * 256 + threadIdx.x;
    if (e < E) atomicAdd(&cnt[dst[e]], 1);
}

// block-level exclusive scan over chunks of 1024; writes per-chunk exclusive scan + chunk total
__global__ __launch_bounds__(256) void scan1_kernel(const int* __restrict__ cnt,
                                                    int* __restrict__ rowptr,
                                                    int* __restrict__ blocksums, int n)
{
    __shared__ int lds[256];
    int t = threadIdx.x;
    int base = blockIdx.x * SCAN_CHUNK + t * 4;
    int v[4]; int s = 0;
    #pragma unroll
    for (int i = 0; i < 4; ++i) {
        v[i] = (base + i < n) ? cnt[base + i] : 0;
        s += v[i];
    }
    lds[t] = s; __syncthreads();
    #pragma unroll
    for (int off = 1; off < 256; off <<= 1) {
        int val = (t >= off) ? lds[t - off] : 0;
        __syncthreads();
        lds[t] += val;
        __syncthreads();
    }
    if (t == 255) blocksums[blockIdx.x] = lds[255];
    int run = (t == 0) ? 0 : lds[t - 1];
    #pragma unroll
    for (int i = 0; i < 4; ++i) {
        if (base + i < n) rowptr[base + i] = run;
        run += v[i];
    }
}

// single-block exclusive scan of block sums (nb <= 256)
__global__ __launch_bounds__(256) void scan2_kernel(int* __restrict__ blocksums, int nb)
{
    __shared__ int lds[256];
    int t = threadIdx.x;
    int v = (t < nb) ? blocksums[t] : 0;
    lds[t] = v; __syncthreads();
    #pragma unroll
    for (int off = 1; off < 256; off <<= 1) {
        int val = (t >= off) ? lds[t - off] : 0;
        __syncthreads();
        lds[t] += val;
        __syncthreads();
    }
    if (t < nb) blocksums[t] = lds[t] - v;   // exclusive
}

// add chunk offsets; produce cursor copy; rowptr[n] = E
__global__ __launch_bounds__(256) void scan3_kernel(int* __restrict__ rowptr,
                                                    int* __restrict__ cursor,
                                                    const int* __restrict__ blocksums,
                                                    int n, int E)
{
    int i = blockIdx.x * 256 + threadIdx.x;
    if (i < n) {
        int r = rowptr[i] + blocksums[i / SCAN_CHUNK];
        rowptr[i] = r;
        cursor[i] = r;
    }
    if (i == 0) rowptr[n] = E;
}

// dst-sorted edge array: edges[pos] = {src, bits(weight)}
__global__ __launch_bounds__(256) void fill_csr_kernel(const int* __restrict__ src,
                                                       const int* __restrict__ dst,
                                                       const float* __restrict__ ew,
                                                       int* __restrict__ cursor,
                                                       int2* __restrict__ edges, int E)
{
    int e = blockIdx.x * 256 + threadIdx.x;
    if (e >= E) return;
    int d = dst[e];
    int pos = atomicAdd(&cursor[d], 1);
    edges[pos] = make_int2(src[e], __float_as_int(ew[e]));
}

// ---------- compute ----------

// h1a = x @ W1  (N x 128 @ 128 x 16)
__global__ __launch_bounds__(256) void gemm1_kernel(const float* __restrict__ x,
                                                    const float* __restrict__ W1,
                                                    float* __restrict__ h1a, int n)
{
    __shared__ float xs[64 * 132];
    __shared__ float ws[16 * 132];
    int tid = threadIdx.x;
    int r0 = blockIdx.x * 64;
    int rows = n - r0; if (rows > 64) rows = 64;

    const float4* xg = (const float4*)(x + (size_t)r0 * NFEAT);
    #pragma unroll
    for (int i = 0; i < 8; ++i) {
        int flat4 = i * 256 + tid;
        int row = flat4 >> 5, k4 = flat4 & 31;
        float4 v = make_float4(0.f, 0.f, 0.f, 0.f);
        if (row < rows) v = xg[flat4];
        *(float4*)&xs[row * 132 + k4 * 4] = v;
    }
    for (int i = tid; i < HID * NFEAT; i += 256) {
        int c = i >> 7, k = i & 127;
        ws[c * 132 + k] = W1[k * HID + c];
    }
    __syncthreads();

    int row = tid >> 2;
    int c0  = (tid & 3) * 4;
    float acc[4] = {0.f, 0.f, 0.f, 0.f};
    #pragma unroll 4
    for (int k4 = 0; k4 < 32; ++k4) {
        float4 xv = *(const float4*)&xs[row * 132 + k4 * 4];
        #pragma unroll
        for (int i = 0; i < 4; ++i) {
            float4 wv = *(const float4*)&ws[(c0 + i) * 132 + k4 * 4];
            acc[i] += xv.x * wv.x + xv.y * wv.y + xv.z * wv.z + xv.w * wv.w;
        }
    }
    if (row < rows)
        *(float4*)&h1a[(size_t)(r0 + row) * HID + c0] =
            make_float4(acc[0], acc[1], acc[2], acc[3]);
}

// out[i] = h[i] + sum_{e: dst=i} w_e * h[src_e]   (16-dim, 4 threads/node)
__global__ __launch_bounds__(256) void gather_agg_kernel(const float* __restrict__ h,
                                                         const int* __restrict__ rowptr,
                                                         const int2* __restrict__ edges,
                                                         float* __restrict__ out, int n)
{
    int gid = blockIdx.x * 256 + threadIdx.x;
    int node = gid >> 2, p = gid & 3;
    if (node >= n) return;
    int beg = rowptr[node], end = rowptr[node + 1];
    const float4* h4 = (const float4*)h;
    float4 acc = h4[node * 4 + p];          // self loop
    for (int j = beg; j < end; ++j) {
        int2 e = edges[j];
        float w = __int_as_float(e.y);
        float4 v = h4[e.x * 4 + p];
        acc.x += w * v.x; acc.y += w * v.y;
        acc.z += w * v.z; acc.w += w * v.w;
    }
    ((float4*)out)[node * 4 + p] = acc;
}

// out = log_softmax(g2 @ W2)
__global__ __launch_bounds__(256) void gemm2_lsm_kernel(const float* __restrict__ h,
                                                        const float* __restrict__ W2,
                                                        float* __restrict__ out, int n)
{
    __shared__ float ws[HID * NCLS];
    int tid = threadIdx.x;
    for (int i = tid; i < HID * NCLS; i += 256) ws[i] = W2[i];
    __syncthreads();
    int r = blockIdx.x * 256 + tid;
    if (r >= n) return;

    float hr[HID];
    const float4* h4 = (const float4*)(h + (size_t)r * HID);
    #pragma unroll
    for (int i = 0; i < 4; ++i) {
        float4 v = h4[i];
        hr[i * 4 + 0] = v.x; hr[i * 4 + 1] = v.y; hr[i * 4 + 2] = v.z; hr[i * 4 + 3] = v.w;
    }
    float acc[NCLS];
    #pragma unroll
    for (int j = 0; j < NCLS; ++j) acc[j] = 0.f;
    #pragma unroll
    for (int k = 0; k < HID; ++k) {
        float hk = hr[k];
        #pragma unroll
        for (int j4 = 0; j4 < NCLS / 4; ++j4) {
            float4 w = *(const float4*)&ws[k * NCLS + j4 * 4];
            acc[j4 * 4 + 0] += hk * w.x;
            acc[j4 * 4 + 1] += hk * w.y;
            acc[j4 * 4 + 2] += hk * w.z;
            acc[j4 * 4 + 3] += hk * w.w;
        }
    }
    float m = acc[0];
    #pragma unroll
    for (int j = 1; j < NCLS; ++j) m = fmaxf(m, acc[j]);
    float ssum = 0.f;
    #pragma unroll
    for (int j = 0; j < NCLS; ++j) ssum += __expf(acc[j] - m);
    float l = m + __logf(ssum);
    float4* o4 = (float4*)(out + (size_t)r * NCLS);
    #pragma unroll
    for (int j4 = 0; j4 < NCLS / 4; ++j4)
        o4[j4] = make_float4(acc[j4 * 4 + 0] - l, acc[j4 * 4 + 1] - l,
                             acc[j4 * 4 + 2] - l, acc[j4 * 4 + 3] - l);
}

extern "C" void kernel_launch(void* const* d_in, const int* in_sizes, int n_in,
                              void* d_out, int out_size, void* d_ws, size_t ws_size,
                              hipStream_t stream)
{
    const float* x  = (const float*)d_in[0];
    const float* ew = (const float*)d_in[1];
    const float* W1 = (const float*)d_in[2];
    const float* W2 = (const float*)d_in[3];
    const int*   ei = (const int*)d_in[4];

    int n = in_sizes[0] / NFEAT;     // 100000
    int E = in_sizes[1];             // 1600000
    const int* src = ei;
    const int* dst = ei + E;
    float* out = (float*)d_out;

    // ---- workspace layout (4B units) ----
    char* w = (char*)d_ws;
    int*  cnt      = (int*)w;                         w += (size_t)n * 4;
    int*  rowptr   = (int*)w;                         w += (size_t)(n + 1) * 4;
    int*  cursor   = (int*)w;                         w += (size_t)n * 4;
    int*  blocksums= (int*)w;                         w += 256 * 4;
    int2* edges    = (int2*)w;                        w += (size_t)E * 8;
    float* h1a     = (float*)w;                       w += (size_t)n * HID * 4;
    float* h1      = (float*)w;                       w += (size_t)n * HID * 4;
    float* g2      = h1a;   // h1a dead after gather1

    int nb = (n + SCAN_CHUNK - 1) / SCAN_CHUNK;       // 98

    // CSR build (graph identical for both layers — build once)
    zero_counts_kernel<<<(n + 255) / 256, 256, 0, stream>>>(cnt, n);
    count_deg_kernel<<<(E + 255) / 256, 256, 0, stream>>>(dst, cnt, E);
    scan1_kernel<<<nb, 256, 0, stream>>>(cnt, rowptr, blocksums, n);
    scan2_kernel<<<1, 256, 0, stream>>>(blocksums, nb);
    scan3_kernel<<<(n + 255) / 256, 256, 0, stream>>>(rowptr, cursor, blocksums, n, E);
    fill_csr_kernel<<<(E + 255) / 256, 256, 0, stream>>>(src, dst, ew, cursor, edges, E);

    // compute
    gemm1_kernel<<<(n + 63) / 64, 256, 0, stream>>>(x, W1, h1a, n);
    gather_agg_kernel<<<(n * 4 + 255) / 256, 256, 0, stream>>>(h1a, rowptr, edges, h1, n);
    gather_agg_kernel<<<(n * 4 + 255) / 256, 256, 0, stream>>>(h1, rowptr, edges, g2, n);
    gemm2_lsm_kernel<<<(n + 255) / 256, 256, 0, stream>>>(g2, W2, out, n);
}